// Round 5
// baseline (115.592 us; speedup 1.0000x reference)
//
#include <hip/hip_runtime.h>
#include <math.h>

#define BATCH 16
#define CH 256
#define IH 128
#define IW 128
#define IHW (IH*IW)
#define KK 7
#define KK2 49
#define NCH 147      // conv output channels (3*49)
#define KDIM 98      // 2 ch * 49 taps
#define OSTR 132     // omO row stride (u32); 132 % 32 == 4 -> <=2-way on b128 writes
#define MSTR 132     // omM row stride (u16)
#define PSTR 135     // P row stride (u32)

typedef __bf16 bf16x8 __attribute__((ext_vector_type(8)));
typedef float f32x4 __attribute__((ext_vector_type(4)));

__device__ __forceinline__ float sigmoidf_(float x){ return 1.0f/(1.0f+__expf(-x)); }
__device__ __forceinline__ unsigned short f2bf(float f){
    union{float f; unsigned u;} v; v.f=f;
    unsigned r = v.u + 0x7FFFu + ((v.u>>16)&1u);
    return (unsigned short)(r>>16);
}
__device__ __forceinline__ float bf2f(unsigned short u){
    union{unsigned u; float f;} v; v.u = ((unsigned)u)<<16; return v.f;
}

// ---------------- BN block-reduce helper ----------------
__device__ __forceinline__ void blockReduce2(float& s, float& q){
    #pragma unroll
    for (int o=32;o>0;o>>=1){ s += __shfl_down(s,o); q += __shfl_down(q,o); }
    __shared__ float ls[8], lq[8];
    int wid  = threadIdx.x >> 6;
    int lane = threadIdx.x & 63;
    if (lane==0){ ls[wid]=s; lq[wid]=q; }
    __syncthreads();
    if (threadIdx.x==0){
        int nw = blockDim.x >> 6;
        s = ls[0]; q = lq[0];
        for (int i=1;i<nw;++i){ s+=ls[i]; q+=lq[i]; }
    }
}

// ---------------- K_pre: streaming partial channel-reduce -----------------------------
// Grid 512 = [b:16][hwq:4][cg:8]. Block reads 32 channels x 16KB CONTIGUOUS chunks
// (4 dwordx4/thread/channel, 2-channel unroll -> 8 loads in flight), accumulating
// 16 positions/thread in registers. Writes (sum,max) partials [cg][b][4096 float4].
__global__ __launch_bounds__(256) void k_pre(const float* __restrict__ x,
                                             float4* __restrict__ psum4,
                                             float4* __restrict__ pmax4){
    const int tid = threadIdx.x;
    const int e   = blockIdx.x;
    const int cg  = e & 7;
    const int hwq = (e >> 3) & 3;
    const int b   = e >> 5;
    const float4* xp = reinterpret_cast<const float4*>(x)
                     + ((size_t)(b*CH + cg*32) * 4096 + hwq*1024 + tid);
    float4 s0={0,0,0,0}, s1={0,0,0,0}, s2={0,0,0,0}, s3={0,0,0,0};
    float4 m0={-3e38f,-3e38f,-3e38f,-3e38f}, m1=m0, m2=m0, m3=m0;
    for (int c=0; c<32; c+=2){
        const float4* p0 = xp + (size_t)c*4096;
        const float4* p1 = xp + (size_t)(c+1)*4096;
        float4 a0 = p0[0],   a1 = p0[256], a2 = p0[512], a3 = p0[768];
        float4 b0 = p1[0],   b1 = p1[256], b2 = p1[512], b3 = p1[768];
        s0.x+=a0.x; s0.y+=a0.y; s0.z+=a0.z; s0.w+=a0.w;
        s1.x+=a1.x; s1.y+=a1.y; s1.z+=a1.z; s1.w+=a1.w;
        s2.x+=a2.x; s2.y+=a2.y; s2.z+=a2.z; s2.w+=a2.w;
        s3.x+=a3.x; s3.y+=a3.y; s3.z+=a3.z; s3.w+=a3.w;
        m0.x=fmaxf(m0.x,a0.x); m0.y=fmaxf(m0.y,a0.y); m0.z=fmaxf(m0.z,a0.z); m0.w=fmaxf(m0.w,a0.w);
        m1.x=fmaxf(m1.x,a1.x); m1.y=fmaxf(m1.y,a1.y); m1.z=fmaxf(m1.z,a1.z); m1.w=fmaxf(m1.w,a1.w);
        m2.x=fmaxf(m2.x,a2.x); m2.y=fmaxf(m2.y,a2.y); m2.z=fmaxf(m2.z,a2.z); m2.w=fmaxf(m2.w,a2.w);
        m3.x=fmaxf(m3.x,a3.x); m3.y=fmaxf(m3.y,a3.y); m3.z=fmaxf(m3.z,a3.z); m3.w=fmaxf(m3.w,a3.w);
        s0.x+=b0.x; s0.y+=b0.y; s0.z+=b0.z; s0.w+=b0.w;
        s1.x+=b1.x; s1.y+=b1.y; s1.z+=b1.z; s1.w+=b1.w;
        s2.x+=b2.x; s2.y+=b2.y; s2.z+=b2.z; s2.w+=b2.w;
        s3.x+=b3.x; s3.y+=b3.y; s3.z+=b3.z; s3.w+=b3.w;
        m0.x=fmaxf(m0.x,b0.x); m0.y=fmaxf(m0.y,b0.y); m0.z=fmaxf(m0.z,b0.z); m0.w=fmaxf(m0.w,b0.w);
        m1.x=fmaxf(m1.x,b1.x); m1.y=fmaxf(m1.y,b1.y); m1.z=fmaxf(m1.z,b1.z); m1.w=fmaxf(m1.w,b1.w);
        m2.x=fmaxf(m2.x,b2.x); m2.y=fmaxf(m2.y,b2.y); m2.z=fmaxf(m2.z,b2.z); m2.w=fmaxf(m2.w,b2.w);
        m3.x=fmaxf(m3.x,b3.x); m3.y=fmaxf(m3.y,b3.y); m3.z=fmaxf(m3.z,b3.z); m3.w=fmaxf(m3.w,b3.w);
    }
    const size_t o4 = (size_t)cg*65536 + (size_t)b*4096 + hwq*1024 + tid;
    psum4[o4        ] = s0;  pmax4[o4        ] = m0;
    psum4[o4 +  256 ] = s1;  pmax4[o4 +  256 ] = m1;
    psum4[o4 +  512 ] = s2;  pmax4[o4 +  512 ] = m2;
    psum4[o4 +  768 ] = s3;  pmax4[o4 +  768 ] = m3;
}

// ---------------- K_mrg: merge 8 channel-group partials -> interleaved xc (blocks<256)
// ----------------        + weight pack into MFMA B order (blocks>=256) -----------------
// xc layout: [B][H][W][2] f32 (c0=avg, c1=max interleaved).
// B column mapping (pairs oy/ox onto same lane):
//   nt 0..5: k=(nt>>1)*16+l15 (0..47), o=2k+(nt&1)
//   nt6 l15==0: o=96; nt7 l15==0: o=97
//   masks: nt6 l15>=1 -> 98+(l15-1); nt7 l15>=1 -> 98+14+l15; nt8 -> 98+30+l15; nt9 l15<3 -> 98+46+l15
// Row mapping k' = m*8+j, m=ks*4+(lane>>4): m<14: ky=m>>1, kx=4*(m&1)+(j>>1), c=j&1; else ZERO.
__global__ __launch_bounds__(256) void k_mrg(const float4* __restrict__ psum4,
                                             const float4* __restrict__ pmax4,
                                             float* __restrict__ xc,
                                             const float* __restrict__ w_off,
                                             unsigned short* __restrict__ bw){
    if (blockIdx.x >= 256){
        int e = (blockIdx.x-256)*256 + threadIdx.x;     // 20480 elements
        int j    = e & 7;
        int lane = (e >> 3) & 63;
        int fs   = e >> 9;                              // 0..39
        int ks   = fs & 3;
        int nt   = fs >> 2;
        int l15  = lane & 15;
        int m    = ks*4 + (lane >> 4);
        int o = -1;
        if (nt < 6){
            int k = (nt>>1)*16 + l15;
            o = 2*k + (nt & 1);
        } else if (nt == 6){
            o = (l15==0) ? 96 : 98 + (l15-1);
        } else if (nt == 7){
            o = (l15==0) ? 97 : 98 + 14 + l15;
        } else if (nt == 8){
            o = 98 + 30 + l15;
        } else {
            o = (l15<3) ? 98 + 46 + l15 : -1;
        }
        float v = 0.f;
        if (o >= 0 && m < 14){
            int ky = m >> 1;
            int kx = 4*(m&1) + (j>>1);
            int c  = j & 1;
            if (kx < KK) v = w_off[(size_t)o*KDIM + c*KK2 + ky*KK + kx];
        }
        bw[e] = f2bf(v);
        return;
    }
    const int g4 = blockIdx.x*256 + threadIdx.x;        // 0..65535 float4 positions
    float4 s = {0.f,0.f,0.f,0.f};
    float4 m = {-3e38f,-3e38f,-3e38f,-3e38f};
    #pragma unroll
    for (int cg=0; cg<8; ++cg){
        float4 a = psum4[(size_t)cg*65536 + g4];
        float4 t = pmax4[(size_t)cg*65536 + g4];
        s.x+=a.x; s.y+=a.y; s.z+=a.z; s.w+=a.w;
        m.x=fmaxf(m.x,t.x); m.y=fmaxf(m.y,t.y); m.z=fmaxf(m.z,t.z); m.w=fmaxf(m.w,t.w);
    }
    const float inv = 1.0f/(float)CH;
    float4 w0 = {s.x*inv, m.x, s.y*inv, m.y};
    float4 w1 = {s.z*inv, m.z, s.w*inv, m.w};
    float4* dst = reinterpret_cast<float4*>(xc) + (size_t)g4*2;
    dst[0] = w0;
    dst[1] = w1;
}

// ---------------- K2: fused MFMA conv + deformable sampling + BN partials ----------------
// One block = one image row (b,h). omO[49][OSTR] u32 = packed (oy|ox) bf16 pair per tap;
// omM[49][MSTR] u16 = mask logits. Sampling reads interleaved xc straight from global (L2-hot).
__global__ __launch_bounds__(256,3) void k_dcn_fused(const float* __restrict__ xc,
    const unsigned short* __restrict__ bw, const float* __restrict__ b_off,
    const float* __restrict__ w_dcn, float* __restrict__ outp, float* __restrict__ partial)
{
    __shared__ __align__(16) unsigned char smem[43104];
    unsigned*       omO = (unsigned*)smem;                  // [49][OSTR] u32 = 25872 B
    unsigned short* omM = (unsigned short*)(smem + 25872);  // [49][MSTR] u16 = 12936 B -> 38808
    unsigned* P = (unsigned*)(smem + 38808);                // [7][PSTR] u32 = 3780 B -> 42588
    float* psum = (float*)(smem + 42592);                   // [128] f32

    const int tid = threadIdx.x;
    const int bh = blockIdx.x;
    const int b  = bh >> 7;
    const int h  = bh & 127;
    const float* img2 = xc + (size_t)b*2*IHW;   // interleaved [H][W][2]

    // phase 0: packed conv-row buffer P[ky][p], p = x+3, rows h-3..h+3 (bf16 c0|c1)
    for (int t = tid; t < 7*PSTR; t += 256){
        int ky = t / PSTR;
        int p  = t - ky*PSTR;
        int xx = p - 3;
        int yy = h - 3 + ky;
        unsigned pk = 0u;
        if (((unsigned)xx < (unsigned)IW) & ((unsigned)yy < (unsigned)IH) & (p < 135)){
            const float2 v = *reinterpret_cast<const float2*>(img2 + 2*(yy*IW + xx));
            pk = (unsigned)f2bf(v.x) | ((unsigned)f2bf(v.y) << 16);
        }
        P[t] = pk;
    }
    __syncthreads();

    // phase 2: MFMA, ks-outer (2 A-frags live). A from P rows, B streamed from global.
    const int wid  = tid >> 6;
    const int lane = tid & 63;
    const int l15  = lane & 15;
    const int lg   = lane >> 4;

    f32x4 acc[2][10];
    #pragma unroll
    for (int i=0;i<2;++i)
        #pragma unroll
        for (int j=0;j<10;++j) acc[i][j] = (f32x4){0.f,0.f,0.f,0.f};

    const bf16x8* bv = reinterpret_cast<const bf16x8*>(bw);
    #pragma unroll
    for (int ks=0; ks<4; ++ks){
        const int m = ks*4 + lg;
        int ky = m >> 1; ky = (ky > 6) ? 6 : ky;
        const int p0 = 4*(m & 1);
        bf16x8 af[2];
        #pragma unroll
        for (int mt=0; mt<2; ++mt){
            const int pix = wid*32 + mt*16 + l15;
            const unsigned* sp = P + ky*PSTR + pix + p0;
            union { unsigned u[4]; bf16x8 v; } uu;
            uu.u[0]=sp[0]; uu.u[1]=sp[1]; uu.u[2]=sp[2]; uu.u[3]=sp[3];
            af[mt] = uu.v;
        }
        #pragma unroll
        for (int nt=0; nt<10; ++nt){
            bf16x8 bfr = bv[(nt*4+ks)*64 + lane];
            acc[0][nt] = __builtin_amdgcn_mfma_f32_16x16x32_bf16(af[0], bfr, acc[0][nt], 0,0,0);
            acc[1][nt] = __builtin_amdgcn_mfma_f32_16x16x32_bf16(af[1], bfr, acc[1][nt], 0,0,0);
        }
    }
    // no barrier needed: omO/omM untouched so far; P not written below

    // phase 3: bias add, pack (oy|ox) u32 pairs + mask logits, vectorized LDS writes
    #pragma unroll
    for (int g=0; g<3; ++g){                     // taps k = g*16 + l15 (0..47)
        const int k = g*16 + l15;
        float2 bo = *reinterpret_cast<const float2*>(b_off + 2*k);
        #pragma unroll
        for (int mt=0; mt<2; ++mt){
            const int pixb = wid*32 + mt*16 + lg*4;
            uint4 wv;
            #pragma unroll
            for (int r=0;r<4;++r){
                unsigned lo = f2bf(acc[mt][2*g  ][r] + bo.x);
                unsigned hi = f2bf(acc[mt][2*g+1][r] + bo.y);
                reinterpret_cast<unsigned*>(&wv)[r] = lo | (hi<<16);
            }
            *reinterpret_cast<uint4*>(omO + k*OSTR + pixb) = wv;
        }
    }
    if (l15 == 0){                               // tap k=48: cols 96 (nt6) / 97 (nt7)
        float2 bo = *reinterpret_cast<const float2*>(b_off + 96);
        #pragma unroll
        for (int mt=0; mt<2; ++mt){
            const int pixb = wid*32 + mt*16 + lg*4;
            uint4 wv;
            #pragma unroll
            for (int r=0;r<4;++r){
                unsigned lo = f2bf(acc[mt][6][r] + bo.x);
                unsigned hi = f2bf(acc[mt][7][r] + bo.y);
                reinterpret_cast<unsigned*>(&wv)[r] = lo | (hi<<16);
            }
            *reinterpret_cast<uint4*>(omO + 48*OSTR + pixb) = wv;
        }
    }
    #pragma unroll
    for (int nt=6; nt<10; ++nt){                 // mask logits
        int k; bool valid;
        if      (nt==6){ k = l15-1;  valid = (l15>=1); }
        else if (nt==7){ k = 14+l15; valid = (l15>=1); }
        else if (nt==8){ k = 30+l15; valid = true; }
        else           { k = 46+l15; valid = (l15<3); }
        if (valid){
            const float bo = b_off[KDIM + k];
            #pragma unroll
            for (int mt=0; mt<2; ++mt){
                const int pixb = wid*32 + mt*16 + lg*4;
                ushort4 wv;
                #pragma unroll
                for (int r=0;r<4;++r)
                    reinterpret_cast<unsigned short*>(&wv)[r] = f2bf(acc[mt][nt][r] + bo);
                *reinterpret_cast<ushort4*>(omM + k*MSTR + pixb) = wv;
            }
        }
    }
    __syncthreads();

    // phase 4: deformable sampling; 2 threads/pixel; branch-free bilinear from global xc
    const int pix  = tid & 127;
    const int half = tid >> 7;
    const int kbeg = half ? 25 : 0;              // half0: k=0..24 (25); half1: 25..48 (24)
    const float pixf = (float)pix;
    const float yb = (float)(h - 3);
    const unsigned* omOp = omO + pix;
    const unsigned short* omMp = omM + pix;
    const float2* g2 = reinterpret_cast<const float2*>(img2);
    int   kx    = half ? 4 : 0;
    float kyf   = half ? 3.f : 0.f;
    float kxm3  = (float)(kx - 3);
    float accv = 0.f;
    #pragma unroll 5
    for (int t=0; t<25; ++t){
        int k = kbeg + t;
        float scale = 1.f;
        if (k > 48){ k = 48; scale = 0.f; }      // dup tap, zeroed (keeps trip constant)
        unsigned oyx = omOp[k*OSTR];
        float oy  = bf2f((unsigned short)(oyx & 0xFFFFu));
        float ox  = bf2f((unsigned short)(oyx >> 16));
        float msk = sigmoidf_(bf2f(omMp[k*MSTR]));
        float ys = yb + (kyf + oy);
        float xs = pixf + (kxm3 + ox);
        float y0f = floorf(ys), x0f = floorf(xs);
        float dy = ys - y0f, dx = xs - x0f;
        int y0 = (int)y0f, x0 = (int)x0f;
        int y1 = y0 + 1,   x1 = x0 + 1;
        float fx0 = ((unsigned)x0 < (unsigned)IW) ? 1.f : 0.f;
        float fx1 = ((unsigned)x1 < (unsigned)IW) ? 1.f : 0.f;
        float fy0 = ((unsigned)y0 < (unsigned)IH) ? 1.f : 0.f;
        float fy1 = ((unsigned)y1 < (unsigned)IH) ? 1.f : 0.f;
        int xc0 = min(max(x0,0),IW-1), xc1 = min(max(x1,0),IW-1);
        int yc0 = min(max(y0,0),IH-1), yc1 = min(max(y1,0),IH-1);
        float w00=(1.f-dy)*(1.f-dx)*fx0;
        float w01=(1.f-dy)*dx      *fx1;
        float w10=dy*(1.f-dx)      *fx0;
        float w11=dy*dx            *fx1;
        float2 a00 = g2[yc0*IW + xc0];
        float2 a01 = g2[yc0*IW + xc1];
        float2 a10 = g2[yc1*IW + xc0];
        float2 a11 = g2[yc1*IW + xc1];
        float s0 = fy0*(a00.x*w00 + a01.x*w01) + fy1*(a10.x*w10 + a11.x*w11);
        float s1 = fy0*(a00.y*w00 + a01.y*w01) + fy1*(a10.y*w10 + a11.y*w11);
        accv += scale * msk * (s0*w_dcn[k] + s1*w_dcn[KK2+k]);
        ++kx; kxm3 += 1.f;
        if (kx == KK){ kx = 0; kxm3 = -3.f; kyf += 1.f; }
    }
    if (half) psum[pix] = accv;
    __syncthreads();
    float o = 0.f;
    if (!half){ o = accv + psum[pix]; outp[bh*IW + pix] = o; }
    float s = o, q = o*o;
    blockReduce2(s,q);
    if (tid==0){ partial[bh] = s; partial[2048+bh] = q; }
}

// ---------------- K3: final normalize; each block redundantly reduces the partials ------
__global__ __launch_bounds__(256) void k_final(const float* __restrict__ outp,
    const float* __restrict__ partial,
    const float* __restrict__ gamma, const float* __restrict__ beta, float* __restrict__ out){
    const int tid = threadIdx.x;
    const float4* ps = reinterpret_cast<const float4*>(partial);
    const float4* pq = reinterpret_cast<const float4*>(partial + 2048);
    float s = 0.f, q = 0.f;
    #pragma unroll
    for (int i = tid; i < 512; i += 256){
        float4 a = ps[i]; s += a.x+a.y+a.z+a.w;
        float4 c = pq[i]; q += c.x+c.y+c.z+c.w;
    }
    blockReduce2(s,q);
    __shared__ float st[2];
    if (tid==0){
        const float N = (float)(BATCH*IHW);
        float mean = s/N;
        float var  = fmaxf(q/N - mean*mean, 0.f);
        st[0]=mean;
        st[1]=rsqrtf(var + 1e-5f);
    }
    __syncthreads();
    float mean = st[0], istd = st[1];
    float g = gamma[0], bt = beta[0];
    int t = blockIdx.x*256 + tid;
    float4 v = reinterpret_cast<const float4*>(outp)[t];
    float4 r;
    r.x = sigmoidf_((v.x-mean)*istd*g + bt);
    r.y = sigmoidf_((v.y-mean)*istd*g + bt);
    r.z = sigmoidf_((v.z-mean)*istd*g + bt);
    r.w = sigmoidf_((v.w-mean)*istd*g + bt);
    reinterpret_cast<float4*>(out)[t] = r;
}

extern "C" void kernel_launch(void* const* d_in, const int* in_sizes, int n_in,
                              void* d_out, int out_size, void* d_ws, size_t ws_size,
                              hipStream_t stream){
    const float* x     = (const float*)d_in[0];
    const float* w_off = (const float*)d_in[1];
    const float* b_off = (const float*)d_in[2];
    const float* w_dcn = (const float*)d_in[3];
    const float* gamma = (const float*)d_in[4];
    const float* beta  = (const float*)d_in[5];
    float* ws = (float*)d_ws;
    float* xc      = ws;                                  // 524288 f32 (2 MB, interleaved)
    float* outp    = ws + 524288;                         // 262144 f32 (1 MB)
    float* partial = ws + 786432;                         // 4096 f32 (sum | sumsq)
    unsigned short* bw = (unsigned short*)(ws + 790544);  // 20480 u16 packed weights
    float4* psum4  = (float4*)(ws + 1048576);             // [8][16][4096] float4 = 8 MB
    float4* pmax4  = (float4*)(ws + 3145728);             // [8][16][4096] float4 = 8 MB

    hipLaunchKernelGGL(k_pre,      dim3(512),  dim3(256), 0, stream, x, psum4, pmax4);
    hipLaunchKernelGGL(k_mrg,      dim3(336),  dim3(256), 0, stream, psum4, pmax4, xc, w_off, bw);
    hipLaunchKernelGGL(k_dcn_fused,dim3(2048), dim3(256), 0, stream, xc, bw, b_off, w_dcn, outp, partial);
    hipLaunchKernelGGL(k_final,    dim3(256),  dim3(256), 0, stream, outp, partial, gamma, beta, (float*)d_out);
}